// Round 4
// baseline (19196.234 us; speedup 1.0000x reference)
//
#include <hip/hip_runtime.h>
#include <math.h>

#define TT 4096
#define HH 1500
#define NB 250     // blocks; each owns 6 hidden units
#define NT 512     // 8 waves: 0..5 matvec+gates+publish (wave = unit),
                   //          6 = x-proj, 7 = dedicated poller (overlaps M)
#define NREP 8     // pub replicas (reader sharding; bid&7 ~ XCD id)

typedef unsigned uv4 __attribute__((ext_vector_type(4)));
typedef _Float16 h2f __attribute__((ext_vector_type(2)));
typedef _Float16 h4f __attribute__((ext_vector_type(4)));

#define ALD4(p)   __hip_atomic_load((p), __ATOMIC_RELAXED, __HIP_MEMORY_SCOPE_AGENT)
#define AST4(p,v) __hip_atomic_store((p), (v), __ATOMIC_RELAXED, __HIP_MEMORY_SCOPE_AGENT)

__device__ __forceinline__ float fast_sigmoid(float z) {
  return 1.0f / (1.0f + __expf(-z));
}
__device__ __forceinline__ float fast_tanh(float z) {
  float az = fabsf(z);
  float e  = __expf(-2.0f * az);
  float r  = (1.0f - e) / (1.0f + e);
  return copysignf(r, z);
}
// fp16 pair dot with fp32 accumulate (v_dot2_f32_f16)
__device__ __forceinline__ float dot2(unsigned wb, unsigned hb, float acc) {
#if __has_builtin(__builtin_amdgcn_fdot2)
  return __builtin_amdgcn_fdot2(__builtin_bit_cast(h2f, wb),
                                __builtin_bit_cast(h2f, hb), acc, false);
#else
  h2f w = __builtin_bit_cast(h2f, wb), h = __builtin_bit_cast(h2f, hb);
  acc = fmaf((float)w.x, (float)h.x, acc);
  return fmaf((float)w.y, (float)h.y, acc);
#endif
}

// R15: schedule restructure (fabric micro-structure exonerated R11-R14).
// - Gates merged into matvec waves: wave u reduces its 4 gate sums, lane 0
//   keeps c in-register, computes h(u), lanes 0..7 publish to 8 replicas.
//   Wave-7 relay + lds_gs + barrier B + G phase deleted.
// - ONE barrier/step: lds_hh and lds_xp double-buffered by parity; the only
//   cross-wave dep (staged h/xp -> matvec) is covered by barrier A.
//   (P(t+2) writes occur after A(t+1) which is after all M(t) reads.)
// - Wave 7 = dedicated poller: with no barrier between M(t-1) and P(t),
//   wave 7 polls tag t+1 WHILE waves 0..5 compute/publish it -> detect
//   latency overlaps matvec; barrier A waits only for stragglers.
// Pub layout = R11/R13 1536-dword slots (best measured; R14's full-line
// layout regressed via +traffic).
__device__ __forceinline__ void poll6(const unsigned* a0, const unsigned* a1,
                                      const unsigned* a2, const unsigned* a3,
                                      const unsigned* a4, const unsigned* a5,
                                      uv4& v0, uv4& v1, uv4& v2,
                                      uv4& v3, uv4& v4, uv4& v5) {
  asm volatile("global_load_dwordx4 %0, %6, off sc0 sc1\n\t"
               "global_load_dwordx4 %1, %7, off sc0 sc1\n\t"
               "global_load_dwordx4 %2, %8, off sc0 sc1\n\t"
               "global_load_dwordx4 %3, %9, off sc0 sc1\n\t"
               "global_load_dwordx4 %4, %10, off sc0 sc1\n\t"
               "global_load_dwordx4 %5, %11, off sc0 sc1\n\t"
               "s_waitcnt vmcnt(0)"
               : "=&v"(v0), "=&v"(v1), "=&v"(v2),
                 "=&v"(v3), "=&v"(v4), "=&v"(v5)
               : "v"(a0), "v"(a1), "v"(a2), "v"(a3), "v"(a4), "v"(a5)
               : "memory");
}
__device__ __forceinline__ unsigned chk4(uv4 v, unsigned tag) {
  return ((v.x & 15u) ^ tag) | ((v.y & 15u) ^ tag)
       | ((v.z & 15u) ^ tag) | ((v.w & 15u) ^ tag);
}
__device__ __forceinline__ h4f cvt4h(uv4 v) {
  h4f r;
  r.x = (_Float16)__uint_as_float(v.x);
  r.y = (_Float16)__uint_as_float(v.y);
  r.z = (_Float16)__uint_as_float(v.z);
  r.w = (_Float16)__uint_as_float(v.w);
  return r;
}

__global__
__attribute__((amdgpu_flat_work_group_size(NT, NT), amdgpu_waves_per_eu(2, 2)))
void lstm_fused(
    const float* __restrict__ x,    // (4096, 20)
    const float* __restrict__ Wih,  // (6000, 20)
    const float* __restrict__ Whh,  // (6000, 1500)
    const float* __restrict__ bih,  // (6000,)
    const float* __restrict__ bhh,  // (6000,)
    const float* __restrict__ W1,   // (1875, 1500)
    const float* __restrict__ b1,   // (1875,)
    const float* __restrict__ W2,   // (20, 1875)
    const float* __restrict__ b2,   // (20,)
    float* __restrict__ out,        // (20,)
    unsigned* __restrict__ ws)
{
  const int tid = threadIdx.x;
  const int bid = blockIdx.x;
  const int wv  = tid >> 6;   // wave 0..7
  const int ln  = tid & 63;

  // pub: [NREP][2][1536] tagged dwords; block b owns dwords 6b..6b+5 of each
  // replica/slot. hidp after.
  unsigned* pub  = ws;
  unsigned* hidp = ws + NREP * 2 * 1536;   // [1875] tagged hid values

  // weights: 24 rows (r=u*4+g) x 1536 halves (1500 + zero pad) = 73,728 B
  __shared__ __align__(16) _Float16 lds_wh[24 * 1536];
  __shared__ __align__(16) _Float16 lds_hh[2][1536]; // h(t) fp16, parity dbuf
  __shared__ __align__(16) float    lds_hf[1536];    // h(TT) fp32 for MLP
  __shared__ float lds_xp[2][24];                    // x-proj dbuf [par][g*6+u]
  float* lds_hd = (float*)lds_wh;                    // alias (block 0, post-loop)
  // total ~86.2 KB > 80 KiB -> exactly 1 block/CU (lockstep chain intact)

  // ---- stage W_hh slice into LDS, converting fp32 -> fp16 ----
  for (int hi = tid; hi < 24 * 1536; hi += NT) {
    const int r = hi / 1536, k = hi - r * 1536;
    const int u = r >> 2, g = r & 3;
    const size_t grow = (size_t)(g * HH + bid * 6 + u) * HH;
    const float v = (k < HH) ? Whh[grow + k] : 0.f;
    lds_wh[hi] = (_Float16)v;
  }
  // zero the pad tails of BOTH h buffers once (halves 1500..1535 never staged)
  if (tid < 72) lds_hh[tid / 36][1500 + (tid % 36)] = (_Float16)0.f;

  // matvec bases (waves 0..5): 192 b128-chunks per row
  const int uu = (wv < 6) ? wv : 0;
  const uv4* wp = ((const uv4*)lds_wh) + (size_t)uu * 4 * 192;

  // ---- wave 6 lanes 0..23: persistent Wih row (g=ln/6, u=ln%6) + x(0) ----
  float4 wx0, wx1, wx2, wx3, wx4;
  float4 xr0, xr1, xr2, xr3, xr4;
  float bias = 0.f;
  if (wv == 6 && ln < 24) {
    const int g = ln / 6, u = ln - g * 6;
    const int row = g * HH + bid * 6 + u;
    const float4* sp = (const float4*)(Wih + row * 20);
    wx0 = sp[0]; wx1 = sp[1]; wx2 = sp[2]; wx3 = sp[3]; wx4 = sp[4];
    bias = bih[row] + bhh[row];
    const float4* xx = (const float4*)x;
    xr0 = xx[0]; xr1 = xx[1]; xr2 = xx[2]; xr3 = xx[3]; xr4 = xx[4];
  }

  float c = 0.f;  // cell state: lane 0 of wave u (unit = wv)

  // init publish: h(0)=0 with tag 1 into ALL replicas, slot 0
  if (tid < 6 * NREP)
    AST4(pub + (tid / 6) * 3072 + 6 * bid + (tid % 6), 1u);

  __syncthreads();   // weights staged

  // this block's poll replica
  unsigned* myrep = pub + (bid & (NREP - 1)) * 3072;

  for (int t = 0; t < TT; ++t) {
    const int s = t & 1;
    const unsigned tag = (unsigned)((t + 1) & 15);

    // ================= P phase =================
    uv4 pw[12];
    if (wv < 6) {
      // weight prefetch only (12 ds_read_b128); h arrives via wave 7
      #pragma unroll
      for (int g = 0; g < 4; ++g) {
        #pragma unroll
        for (int m = 0; m < 3; ++m) pw[g * 3 + m] = wp[g * 192 + ln + 64 * m];
      }
    } else if (wv == 6) {
      if (ln < 24) {
        // x-projection for step t (from registers, h-independent)
        float sx = bias;
        sx += wx0.x*xr0.x + wx0.y*xr0.y + wx0.z*xr0.z + wx0.w*xr0.w;
        sx += wx1.x*xr1.x + wx1.y*xr1.y + wx1.z*xr1.z + wx1.w*xr1.w;
        sx += wx2.x*xr2.x + wx2.y*xr2.y + wx2.z*xr2.z + wx2.w*xr2.w;
        sx += wx3.x*xr3.x + wx3.y*xr3.y + wx3.z*xr3.z + wx3.w*xr3.w;
        sx += wx4.x*xr4.x + wx4.y*xr4.y + wx4.z*xr4.z + wx4.w*xr4.w;
        lds_xp[s][ln] = sx;
        if (t + 1 < TT) {   // prefetch x(t+1)
          const float4* xx = (const float4*)(x + 20 * (t + 1));
          xr0 = xx[0]; xr1 = xx[1]; xr2 = xx[2]; xr3 = xx[3]; xr4 = xx[4];
        }
      }
    } else {
      // ---- wave 7: poll 6 chunks/lane; OVERLAPS other blocks' M(t-1) ----
      const unsigned* bse = myrep + s * 1536 + (ln << 2);
      const int live5 = (ln < 55);        // chunk 320+ln < 375
      uv4 v0, v1, v2, v3, v4, v5;
      for (;;) {
        poll6(bse, bse + 256, bse + 512, bse + 768, bse + 1024, bse + 1280,
              v0, v1, v2, v3, v4, v5);
        unsigned miss = chk4(v0, tag) | chk4(v1, tag) | chk4(v2, tag)
                      | chk4(v3, tag) | chk4(v4, tag);
        if (live5) miss |= chk4(v5, tag);
        if (!__any(miss != 0u)) break;
        __builtin_amdgcn_s_sleep(1);
      }
      _Float16* hb = lds_hh[s];
      *(h4f*)(hb + (ln << 2))        = cvt4h(v0);
      *(h4f*)(hb + (ln << 2) + 256)  = cvt4h(v1);
      *(h4f*)(hb + (ln << 2) + 512)  = cvt4h(v2);
      *(h4f*)(hb + (ln << 2) + 768)  = cvt4h(v3);
      *(h4f*)(hb + (ln << 2) + 1024) = cvt4h(v4);
      if (live5) *(h4f*)(hb + (ln << 2) + 1280) = cvt4h(v5);
    }
    __syncthreads();   // ---- A: h(t) fp16 + xp(t) staged ----

    // ================= M phase: matvec + gates + publish (waves 0..5) =====
    if (wv < 6) {
      const uv4* hp = (const uv4*)lds_hh[s];
      uv4 hv[3];
      #pragma unroll
      for (int m = 0; m < 3; ++m) hv[m] = hp[ln + 64 * m];
      float a[4] = {0.f, 0.f, 0.f, 0.f};
      #pragma unroll
      for (int g = 0; g < 4; ++g) {
        #pragma unroll
        for (int m = 0; m < 3; ++m) {
          const uv4 q = pw[g * 3 + m], h = hv[m];
          a[g] = dot2(q.x, h.x, a[g]);
          a[g] = dot2(q.y, h.y, a[g]);
          a[g] = dot2(q.z, h.z, a[g]);
          a[g] = dot2(q.w, h.w, a[g]);
        }
      }
      // fold-select reduce: after this, lanes of quartet q all hold gate q
      #pragma unroll
      for (int g = 0; g < 4; ++g) {
        a[g] += __shfl_xor(a[g], 16, 64);
        a[g] += __shfl_xor(a[g], 32, 64);
      }
      const int q4 = ln >> 4;
      float v = (q4 == 0) ? a[0] : (q4 == 1) ? a[1] : (q4 == 2) ? a[2] : a[3];
      v += __shfl_xor(v, 1, 64);
      v += __shfl_xor(v, 2, 64);
      v += __shfl_xor(v, 4, 64);
      v += __shfl_xor(v, 8, 64);
      // per-group activation (i,f,o: sigmoid; g: tanh), then gather to lane 0
      const float z = v + lds_xp[s][q4 * 6 + wv];
      const float act = (q4 == 2) ? fast_tanh(z) : fast_sigmoid(z);
      const float i_ = __shfl(act, 0, 64);
      const float f_ = __shfl(act, 16, 64);
      const float g_ = __shfl(act, 32, 64);
      const float o_ = __shfl(act, 48, 64);
      unsigned bits = 0u;
      if (ln == 0) {
        c = f_ * c + i_ * g_;
        const float hn = o_ * fast_tanh(c);
        bits = (__float_as_uint(hn) & ~15u) | (unsigned)((t + 2) & 15);
      }
      bits = (unsigned)__shfl((int)bits, 0, 64);
      // publish unit wv to all 8 replicas (lanes 0..7), slot (t+1)&1
      if (ln < NREP)
        AST4(pub + ln * 3072 + ((t + 1) & 1) * 1536 + 6 * bid + wv, bits);
    }
  }

  // ---- final gather h(TT) fp32 into lds_hf (slot 0, tag 1) ----
  {
    const unsigned tagf = (unsigned)((TT + 1) & 15);
    if (tid < 375) {
      const unsigned* ap = myrep + (tid << 2);   // slot 0 of own replica
      uv4 v;
      for (;;) {
        asm volatile("global_load_dwordx4 %0, %1, off sc0 sc1\n\t"
                     "s_waitcnt vmcnt(0)"
                     : "=&v"(v) : "v"(ap) : "memory");
        if (!chk4(v, tagf)) break;
        __builtin_amdgcn_s_sleep(1);
      }
      float4 f = {__uint_as_float(v.x), __uint_as_float(v.y),
                  __uint_as_float(v.z), __uint_as_float(v.w)};
      *(float4*)(lds_hf + (tid << 2)) = f;
    } else if (tid < 384) {
      float4 z4 = {0.f, 0.f, 0.f, 0.f};
      *(float4*)(lds_hf + (tid << 2)) = z4;
    }
  }
  __syncthreads();

  // ---- MLP layer 1: wave wv computes row r = bid + 250*wv ----
  {
    const float4* h4 = (const float4*)lds_hf;
    const int r = bid + 250 * wv;
    if (r < 1875) {
      const float4* wrow = (const float4*)(W1 + (size_t)r * HH);
      float ss = 0.f;
      #pragma unroll
      for (int m = 0; m < 6; ++m) {
        const int idx = ln + 64 * m;
        if (idx < 375) {
          const float4 a = wrow[idx], hv = h4[idx];
          ss += a.x*hv.x + a.y*hv.y + a.z*hv.z + a.w*hv.w;
        }
      }
      #pragma unroll
      for (int off = 32; off > 0; off >>= 1) ss += __shfl_xor(ss, off, 64);
      if (ln == 0) {
        const float vv = ss + b1[r];
        AST4(hidp + r, (__float_as_uint(vv) & ~15u) | 5u);  // tag 5 != poison 10
      }
    }
  }
  if (bid != 0) return;

  // ---- block 0: gather hid (into lds_wh alias), MLP layer 2, write out ----
  __syncthreads();
  for (int j = tid; j < 1875; j += NT) {
    unsigned bts;
    for (;;) {
      bts = ALD4(hidp + j);
      if ((bts & 15u) == 5u) break;
      __builtin_amdgcn_s_sleep(1);
    }
    lds_hd[j] = __uint_as_float(bts);
  }
  __syncthreads();

  for (int r = wv; r < 20; r += 8) {
    float ss = 0.f;
    for (int k = ln; k < 1875; k += 64)
      ss = fmaf(W2[(size_t)r * 1875 + k], lds_hd[k], ss);
    #pragma unroll
    for (int off = 32; off > 0; off >>= 1) ss += __shfl_xor(ss, off, 64);
    if (ln == 0) out[r] = ss + b2[r];
  }
}

extern "C" void kernel_launch(void* const* d_in, const int* in_sizes, int n_in,
                              void* d_out, int out_size, void* d_ws, size_t ws_size,
                              hipStream_t stream) {
  const float* x   = (const float*)d_in[0];
  const float* Wih = (const float*)d_in[1];
  const float* Whh = (const float*)d_in[2];
  const float* bih = (const float*)d_in[3];
  const float* bhh = (const float*)d_in[4];
  const float* W1  = (const float*)d_in[5];
  const float* b1  = (const float*)d_in[6];
  const float* W2  = (const float*)d_in[7];
  const float* b2  = (const float*)d_in[8];
  float* out   = (float*)d_out;
  unsigned* ws = (unsigned*)d_ws;   // uses ~106 KB (8 pub replicas + hidp)

  // 250 blocks x 512 threads, ~86 KB LDS (>80 KiB -> 1 block/CU), 250 <= 256
  // CUs: all blocks co-resident -> the tagged exchange cannot deadlock.
  hipLaunchKernelGGL(lstm_fused, dim3(NB), dim3(NT), 0, stream,
                     x, Wih, Whh, bih, bhh, W1, b1, W2, b2, out, ws);
}

// Round 5
// 12799.757 us; speedup vs baseline: 1.4997x; 1.4997x over previous
//
#include <hip/hip_runtime.h>
#include <math.h>

#define TT 4096
#define HH 1500
#define NB 250     // blocks; each owns 6 hidden units
#define NT 512     // 8 waves: 0..5 matvec + pipelined poll (1 lane = 1 chunk),
                   //          6 = x-proj, 7 = gates + publish
#define NREP 8     // pub replicas (reader sharding; bid&7 ~ XCD id)

typedef unsigned uv4 __attribute__((ext_vector_type(4)));
typedef _Float16 h2f __attribute__((ext_vector_type(2)));
typedef _Float16 h4f __attribute__((ext_vector_type(4)));

#define ALD4(p)   __hip_atomic_load((p), __ATOMIC_RELAXED, __HIP_MEMORY_SCOPE_AGENT)
#define AST4(p,v) __hip_atomic_store((p), (v), __ATOMIC_RELAXED, __HIP_MEMORY_SCOPE_AGENT)

__device__ __forceinline__ float fast_sigmoid(float z) {
  return 1.0f / (1.0f + __expf(-z));
}
__device__ __forceinline__ float fast_tanh(float z) {
  float az = fabsf(z);
  float e  = __expf(-2.0f * az);
  float r  = (1.0f - e) / (1.0f + e);
  return copysignf(r, z);
}
// fp16 pair dot with fp32 accumulate (v_dot2_f32_f16)
__device__ __forceinline__ float dot2(unsigned wb, unsigned hb, float acc) {
#if __has_builtin(__builtin_amdgcn_fdot2)
  return __builtin_amdgcn_fdot2(__builtin_bit_cast(h2f, wb),
                                __builtin_bit_cast(h2f, hb), acc, false);
#else
  h2f w = __builtin_bit_cast(h2f, wb), h = __builtin_bit_cast(h2f, hb);
  acc = fmaf((float)w.x, (float)h.x, acc);
  return fmaf((float)w.y, (float)h.y, acc);
#endif
}

// R16: pipelined spin (structure = R13, best-measured family).
// R15 post-mortem: 6-wave publish fragmented writes (WRITE 1.5GB, 48 partial
// line-writes/step) -> reverted to single coalesced wave-7 publish.
// Remaining theory: detect SAMPLING QUANTIZATION + straggler tail. All prior
// polls sample once per fabric latency L (~600-800cy: load,vmcnt(0),check,
// sleep64) -> detect = arrival + U(0,L); step = max over 250 blocks ~ +3.3
// sigma of tail. Fix: depth-3 rolling pipeline ON THE SAME DEST REGS
// (v[60:63], reserved via clobber; all in-flight loads confined to one asm
// block): 2 prelude issues, then {issue 1, vmcnt(2), check} -> a fresh
// sample lands every ~L/3. Per-dword tags make epoch tearing harmless (each
// dword is an individually valid sample; slot content write-once per
// period). Wave-uniform exit (vccnz loop), vmcnt(0) drain = identical data.
__device__ __forceinline__ uv4 spin_poll(const unsigned* ap, unsigned tag,
                                         unsigned msk) {
  unsigned x0, x1, x2, x3, t, acc;
  asm volatile(
      "global_load_dwordx4 v[60:63], %[ap], off sc0 sc1\n\t"
      "global_load_dwordx4 v[60:63], %[ap], off sc0 sc1\n\t"
      "2:\n\t"
      "global_load_dwordx4 v[60:63], %[ap], off sc0 sc1\n\t"
      "s_waitcnt vmcnt(2)\n\t"
      "v_xor_b32 %[t], %[tg], v60\n\t"
      "v_and_b32 %[acc], 15, %[t]\n\t"
      "v_xor_b32 %[t], %[tg], v61\n\t"
      "v_and_or_b32 %[acc], %[t], 15, %[acc]\n\t"
      "v_xor_b32 %[t], %[tg], v62\n\t"
      "v_and_or_b32 %[acc], %[t], 15, %[acc]\n\t"
      "v_xor_b32 %[t], %[tg], v63\n\t"
      "v_and_or_b32 %[acc], %[t], 15, %[acc]\n\t"
      "v_and_b32 %[acc], %[mk], %[acc]\n\t"
      "v_cmp_ne_u32 vcc, 0, %[acc]\n\t"
      "s_cbranch_vccnz 2b\n\t"
      "s_waitcnt vmcnt(0)\n\t"
      "v_mov_b32 %[x0], v60\n\t"
      "v_mov_b32 %[x1], v61\n\t"
      "v_mov_b32 %[x2], v62\n\t"
      "v_mov_b32 %[x3], v63"
      : [x0]"=v"(x0), [x1]"=v"(x1), [x2]"=v"(x2), [x3]"=v"(x3),
        [t]"=&v"(t), [acc]"=&v"(acc)
      : [ap]"v"(ap), [tg]"v"(tag), [mk]"v"(msk)
      : "memory", "vcc", "v60", "v61", "v62", "v63");
  uv4 r;
  r.x = x0; r.y = x1; r.z = x2; r.w = x3;
  return r;
}
__device__ __forceinline__ h4f cvt4h(uv4 v) {
  h4f r;
  r.x = (_Float16)__uint_as_float(v.x);
  r.y = (_Float16)__uint_as_float(v.y);
  r.z = (_Float16)__uint_as_float(v.z);
  r.w = (_Float16)__uint_as_float(v.w);
  return r;
}

__global__
__attribute__((amdgpu_flat_work_group_size(NT, NT), amdgpu_waves_per_eu(2, 2)))
void lstm_fused(
    const float* __restrict__ x,    // (4096, 20)
    const float* __restrict__ Wih,  // (6000, 20)
    const float* __restrict__ Whh,  // (6000, 1500)
    const float* __restrict__ bih,  // (6000,)
    const float* __restrict__ bhh,  // (6000,)
    const float* __restrict__ W1,   // (1875, 1500)
    const float* __restrict__ b1,   // (1875,)
    const float* __restrict__ W2,   // (20, 1875)
    const float* __restrict__ b2,   // (20,)
    float* __restrict__ out,        // (20,)
    unsigned* __restrict__ ws)
{
  const int tid = threadIdx.x;
  const int bid = blockIdx.x;
  const int wv  = tid >> 6;   // wave 0..7
  const int ln  = tid & 63;

  // pub: [NREP][2][1536] tagged dwords; block b owns dwords 6b..6b+5 of each
  // replica/slot. hidp after.
  unsigned* pub  = ws;
  unsigned* hidp = ws + NREP * 2 * 1536;   // [1875] tagged hid values

  // weights: 24 rows (r=u*4+g) x 1536 halves (1500 + zero pad) = 73,728 B
  __shared__ __align__(16) _Float16 lds_wh[24 * 1536];
  __shared__ __align__(16) _Float16 lds_hh[1536];  // h(t) as fp16
  __shared__ __align__(16) float    lds_hf[1536];  // h(TT) fp32 for MLP
  __shared__ float lds_xp[2][24];                  // x-proj dbuf: [par][g*6+u]
  __shared__ float lds_gs[4][6];                   // gate sums: [g][u]
  float* lds_hd = (float*)lds_wh;                  // alias (block 0, post-loop)
  // total ~83.1 KB > 80 KiB -> exactly 1 block/CU (lockstep chain intact)

  // ---- stage W_hh slice into LDS, converting fp32 -> fp16 ----
  for (int hi = tid; hi < 24 * 1536; hi += NT) {
    const int r = hi / 1536, k = hi - r * 1536;
    const int u = r >> 2, g = r & 3;
    const size_t grow = (size_t)(g * HH + bid * 6 + u) * HH;
    const float v = (k < HH) ? Whh[grow + k] : 0.f;
    lds_wh[hi] = (_Float16)v;
  }
  // zero the pad tail of lds_hh once (chunks 375..383 are never polled)
  if (tid < 36) lds_hh[1500 + tid] = (_Float16)0.f;

  // matvec bases (waves 0..5): 192 b128-chunks per row
  const int uu = (wv < 6) ? wv : 0;
  const uv4* wp = ((const uv4*)lds_wh) + (size_t)uu * 4 * 192;
  const uv4* hp = (const uv4*)lds_hh;

  // ---- wave 6 lanes 0..23: persistent Wih row (g=ln/6, u=ln%6) + x(0) ----
  float4 wx0, wx1, wx2, wx3, wx4;
  float4 xr0, xr1, xr2, xr3, xr4;
  float bias = 0.f;
  if (wv == 6 && ln < 24) {
    const int g = ln / 6, u = ln - g * 6;
    const int row = g * HH + bid * 6 + u;
    const float4* s = (const float4*)(Wih + row * 20);
    wx0 = s[0]; wx1 = s[1]; wx2 = s[2]; wx3 = s[3]; wx4 = s[4];
    bias = bih[row] + bhh[row];
    const float4* xx = (const float4*)x;
    xr0 = xx[0]; xr1 = xx[1]; xr2 = xx[2]; xr3 = xx[3]; xr4 = xx[4];
  }

  float c = 0.f;  // cell state: wave 7 lanes 0..5 (unit = ln)

  // init publish: h(0)=0 with tag 1 into ALL replicas, slot 0
  if (tid < 6 * NREP)
    AST4(pub + (tid / 6) * 3072 + 6 * bid + (tid % 6), 1u);

  __syncthreads();   // weights staged

  // this block's poll replica
  unsigned* myrep = pub + (bid & (NREP - 1)) * 3072;

  // per-lane poll binding (waves 0..5): lane ck polls chunk ck
  const int ck    = (wv << 6) | ln;            // 0..383; live 0..374
  const int ckc   = (ck < 375) ? ck : 374;     // dead lanes re-poll 374
  const unsigned mskp = (ck < 375) ? 0xFFFFFFFFu : 0u;

  for (int t = 0; t < TT; ++t) {
    const int s = t & 1;
    const unsigned tag = (unsigned)((t + 1) & 15);

    // ================= P phase (pre-A) =================
    uv4 pw[12];
    if (wv < 6) {
      // weight prefetch: 12 ds_read_b128 issue first (lgkmcnt), overlap poll
      #pragma unroll
      for (int g = 0; g < 4; ++g) {
        #pragma unroll
        for (int m = 0; m < 3; ++m) pw[g * 3 + m] = wp[g * 192 + ln + 64 * m];
      }
      // ---- per-lane pipelined spin (depth-3 rolling, ~L/3 sampling) ----
      const unsigned* ap = myrep + s * 1536 + (ckc << 2);
      const uv4 v = spin_poll(ap, tag, mskp);
      if (ck < 375) *(h4f*)(lds_hh + (ck << 2)) = cvt4h(v);
    } else if (wv == 6 && ln < 24) {
      // x-projection for step t (from registers, h-independent)
      float sx = bias;
      sx += wx0.x*xr0.x + wx0.y*xr0.y + wx0.z*xr0.z + wx0.w*xr0.w;
      sx += wx1.x*xr1.x + wx1.y*xr1.y + wx1.z*xr1.z + wx1.w*xr1.w;
      sx += wx2.x*xr2.x + wx2.y*xr2.y + wx2.z*xr2.z + wx2.w*xr2.w;
      sx += wx3.x*xr3.x + wx3.y*xr3.y + wx3.z*xr3.z + wx3.w*xr3.w;
      sx += wx4.x*xr4.x + wx4.y*xr4.y + wx4.z*xr4.z + wx4.w*xr4.w;
      lds_xp[s][ln] = sx;
    }
    __syncthreads();   // ---- A: h(t) fp16, xp(t) staged ----

    // ================= M phase =================
    if (wv < 6) {
      uv4 hv[3];
      #pragma unroll
      for (int m = 0; m < 3; ++m) hv[m] = hp[ln + 64 * m];
      float a[4] = {0.f, 0.f, 0.f, 0.f};
      #pragma unroll
      for (int g = 0; g < 4; ++g) {
        #pragma unroll
        for (int m = 0; m < 3; ++m) {
          const uv4 q = pw[g * 3 + m], h = hv[m];
          a[g] = dot2(q.x, h.x, a[g]);
          a[g] = dot2(q.y, h.y, a[g]);
          a[g] = dot2(q.z, h.z, a[g]);
          a[g] = dot2(q.w, h.w, a[g]);
        }
      }
      // fold-select reduce: 12 swizzles + 1 ds_write
      #pragma unroll
      for (int g = 0; g < 4; ++g) {
        a[g] += __shfl_xor(a[g], 16, 64);
        a[g] += __shfl_xor(a[g], 32, 64);
      }
      const int q4 = ln >> 4;
      float v = (q4 == 0) ? a[0] : (q4 == 1) ? a[1] : (q4 == 2) ? a[2] : a[3];
      v += __shfl_xor(v, 1, 64);
      v += __shfl_xor(v, 2, 64);
      v += __shfl_xor(v, 4, 64);
      v += __shfl_xor(v, 8, 64);
      if ((ln & 15) == 0) lds_gs[q4][wv] = v;
    } else if (wv == 6 && ln < 24 && (t + 1) < TT) {
      // prefetch x(t+1) while waves 0-5 compute
      const float4* xx = (const float4*)(x + 20 * (t + 1));
      xr0 = xx[0]; xr1 = xx[1]; xr2 = xx[2]; xr3 = xx[3]; xr4 = xx[4];
    }
    __syncthreads();   // ---- B: gate sums ready ----

    // ================= G phase: wave 7 only =================
    if (wv == 7) {
      unsigned bits = 0u;
      if (ln < 6) {
        const int u = ln;
        const float zi = lds_gs[0][u] + lds_xp[s][0 + u];
        const float zf = lds_gs[1][u] + lds_xp[s][6 + u];
        const float zg = lds_gs[2][u] + lds_xp[s][12 + u];
        const float zo = lds_gs[3][u] + lds_xp[s][18 + u];
        const float ig = fast_sigmoid(zi);
        const float fg = fast_sigmoid(zf);
        const float gg = fast_tanh(zg);
        const float og = fast_sigmoid(zo);
        c = fg * c + ig * gg;
        const float hn = og * fast_tanh(c);
        bits = (__float_as_uint(hn) & ~15u) | (unsigned)((t + 2) & 15);
      }
      // broadcast 6 tagged dwords to lanes 0..47; store to all 8 replicas
      const int u6 = ln % 6;
      const unsigned myb = (unsigned)__shfl((int)bits, u6, 64);
      if (ln < 6 * NREP) {
        const int rep = ln / 6;
        AST4(pub + rep * 3072 + ((t + 1) & 1) * 1536 + 6 * bid + u6, myb);
      }
    }
  }

  // ---- final gather h(TT) fp32 into lds_hf (slot 0, tag 1) ----
  {
    const unsigned tagf = (unsigned)((TT + 1) & 15);
    if (tid < 375) {
      const unsigned* ap = myrep + (tid << 2);   // slot 0 of own replica
      uv4 v;
      for (;;) {
        asm volatile("global_load_dwordx4 %0, %1, off sc0 sc1\n\t"
                     "s_waitcnt vmcnt(0)"
                     : "=&v"(v) : "v"(ap) : "memory");
        const unsigned miss = ((v.x & 15u) ^ tagf) | ((v.y & 15u) ^ tagf)
                            | ((v.z & 15u) ^ tagf) | ((v.w & 15u) ^ tagf);
        if (!miss) break;
        __builtin_amdgcn_s_sleep(1);
      }
      float4 f = {__uint_as_float(v.x), __uint_as_float(v.y),
                  __uint_as_float(v.z), __uint_as_float(v.w)};
      *(float4*)(lds_hf + (tid << 2)) = f;
    } else if (tid < 384) {
      float4 z4 = {0.f, 0.f, 0.f, 0.f};
      *(float4*)(lds_hf + (tid << 2)) = z4;
    }
  }
  __syncthreads();

  // ---- MLP layer 1: wave wv computes row r = bid + 250*wv ----
  {
    const float4* h4 = (const float4*)lds_hf;
    const int r = bid + 250 * wv;
    if (r < 1875) {
      const float4* wrow = (const float4*)(W1 + (size_t)r * HH);
      float ss = 0.f;
      #pragma unroll
      for (int m = 0; m < 6; ++m) {
        const int idx = ln + 64 * m;
        if (idx < 375) {
          const float4 a = wrow[idx], hv = h4[idx];
          ss += a.x*hv.x + a.y*hv.y + a.z*hv.z + a.w*hv.w;
        }
      }
      #pragma unroll
      for (int off = 32; off > 0; off >>= 1) ss += __shfl_xor(ss, off, 64);
      if (ln == 0) {
        const float vv = ss + b1[r];
        AST4(hidp + r, (__float_as_uint(vv) & ~15u) | 5u);  // tag 5 != poison 10
      }
    }
  }
  if (bid != 0) return;

  // ---- block 0: gather hid (into lds_wh alias), MLP layer 2, write out ----
  __syncthreads();
  for (int j = tid; j < 1875; j += NT) {
    unsigned bts;
    for (;;) {
      bts = ALD4(hidp + j);
      if ((bts & 15u) == 5u) break;
      __builtin_amdgcn_s_sleep(1);
    }
    lds_hd[j] = __uint_as_float(bts);
  }
  __syncthreads();

  for (int r = wv; r < 20; r += 8) {
    float ss = 0.f;
    for (int k = ln; k < 1875; k += 64)
      ss = fmaf(W2[(size_t)r * 1875 + k], lds_hd[k], ss);
    #pragma unroll
    for (int off = 32; off > 0; off >>= 1) ss += __shfl_xor(ss, off, 64);
    if (ln == 0) out[r] = ss + b2[r];
  }
}

extern "C" void kernel_launch(void* const* d_in, const int* in_sizes, int n_in,
                              void* d_out, int out_size, void* d_ws, size_t ws_size,
                              hipStream_t stream) {
  const float* x   = (const float*)d_in[0];
  const float* Wih = (const float*)d_in[1];
  const float* Whh = (const float*)d_in[2];
  const float* bih = (const float*)d_in[3];
  const float* bhh = (const float*)d_in[4];
  const float* W1  = (const float*)d_in[5];
  const float* b1  = (const float*)d_in[6];
  const float* W2  = (const float*)d_in[7];
  const float* b2  = (const float*)d_in[8];
  float* out   = (float*)d_out;
  unsigned* ws = (unsigned*)d_ws;   // uses ~106 KB (8 pub replicas + hidp)

  // 250 blocks x 512 threads, ~83 KB LDS (>80 KiB -> 1 block/CU), 250 <= 256
  // CUs: all blocks co-resident -> the tagged exchange cannot deadlock.
  hipLaunchKernelGGL(lstm_fused, dim3(NB), dim3(NT), 0, stream,
                     x, Wih, Whh, bih, bhh, W1, b1, W2, b2, out, ws);
}

// Round 6
// 10242.240 us; speedup vs baseline: 1.8742x; 1.2497x over previous
//
#include <hip/hip_runtime.h>
#include <math.h>

#define TT 4096
#define HH 1500
#define NB 125     // blocks; each owns 12 hidden units (R17: halved population)
#define NT 512     // 8 waves: 0..5 matvec (wave = 2 units, 8 gate rows),
                   //          6 = x-proj + poll, 7 = poll + gates + publish
#define NREP 8     // pub replicas (reader sharding; bid&7 ~ XCD id)

typedef unsigned uv4 __attribute__((ext_vector_type(4)));
typedef _Float16 h2f __attribute__((ext_vector_type(2)));
typedef _Float16 h4f __attribute__((ext_vector_type(4)));

#define ALD4(p)   __hip_atomic_load((p), __ATOMIC_RELAXED, __HIP_MEMORY_SCOPE_AGENT)
#define AST4(p,v) __hip_atomic_store((p), (v), __ATOMIC_RELAXED, __HIP_MEMORY_SCOPE_AGENT)
#define AST8(p,v) __hip_atomic_store((p), (v), __ATOMIC_RELAXED, __HIP_MEMORY_SCOPE_AGENT)

__device__ __forceinline__ float fast_sigmoid(float z) {
  return 1.0f / (1.0f + __expf(-z));
}
__device__ __forceinline__ float fast_tanh(float z) {
  float az = fabsf(z);
  float e  = __expf(-2.0f * az);
  float r  = (1.0f - e) / (1.0f + e);
  return copysignf(r, z);
}
// fp16 pair dot with fp32 accumulate (v_dot2_f32_f16)
__device__ __forceinline__ float dot2(unsigned wb, unsigned hb, float acc) {
#if __has_builtin(__builtin_amdgcn_fdot2)
  return __builtin_amdgcn_fdot2(__builtin_bit_cast(h2f, wb),
                                __builtin_bit_cast(h2f, hb), acc, false);
#else
  h2f w = __builtin_bit_cast(h2f, wb), h = __builtin_bit_cast(h2f, hb);
  acc = fmaf((float)w.x, (float)h.x, acc);
  return fmaf((float)w.y, (float)h.y, acc);
#endif
}

// R17: population halving. R11-R16 ledger: every poll/publish MICRO-variation
// (replicas -12%, request width -7%, coupling 0, line-exclusive -10%,
// schedule overlap -45%, sampling rate -20%) bounces off ~6100 cy/step.
// The untested structural lever: N=250 participants. Step period = max over
// N of detect latency, and fabric load scales with N. This kernel = R12
// (best measured, 10.47ms) ported verbatim to 125 blocks x 12 units:
// 48 W_hh rows in LDS (147KB, still 1 block/CU), waves 0..5 = 2 units each
// (24 b128 prefetch, dual accumulators), wave 7 = 12 gates, publish 12
// contiguous dwords x 8 replicas (48 lanes x dwordx2). Poll side bit-
// identical to R12: 1536-dword slots, 128 lanes x 12 dwords (3x dwordx4).
__device__ __forceinline__ void poll3(const unsigned* a0, const unsigned* a1,
                                      const unsigned* a2,
                                      uv4& v0, uv4& v1, uv4& v2) {
  asm volatile(
      "global_load_dwordx4 %0, %3, off sc0 sc1\n\t"
      "global_load_dwordx4 %1, %4, off sc0 sc1\n\t"
      "global_load_dwordx4 %2, %5, off sc0 sc1\n\t"
      "s_waitcnt vmcnt(0)"
      : "=&v"(v0), "=&v"(v1), "=&v"(v2)
      : "v"(a0), "v"(a1), "v"(a2)
      : "memory");
}
__device__ __forceinline__ h4f cvt4h(uv4 v) {
  h4f r;
  r.x = (_Float16)__uint_as_float(v.x);
  r.y = (_Float16)__uint_as_float(v.y);
  r.z = (_Float16)__uint_as_float(v.z);
  r.w = (_Float16)__uint_as_float(v.w);
  return r;
}

__global__
__attribute__((amdgpu_flat_work_group_size(NT, NT), amdgpu_waves_per_eu(2, 2)))
void lstm_fused(
    const float* __restrict__ x,    // (4096, 20)
    const float* __restrict__ Wih,  // (6000, 20)
    const float* __restrict__ Whh,  // (6000, 1500)
    const float* __restrict__ bih,  // (6000,)
    const float* __restrict__ bhh,  // (6000,)
    const float* __restrict__ W1,   // (1875, 1500)
    const float* __restrict__ b1,   // (1875,)
    const float* __restrict__ W2,   // (20, 1875)
    const float* __restrict__ b2,   // (20,)
    float* __restrict__ out,        // (20,)
    unsigned* __restrict__ ws)
{
  const int tid = threadIdx.x;
  const int bid = blockIdx.x;
  const int wv  = tid >> 6;   // wave 0..7
  const int ln  = tid & 63;

  // pub: [NREP][2][1536] tagged dwords; block b owns dwords 12b..12b+11 of
  // each replica/slot. hidp after.
  unsigned* pub  = ws;
  unsigned* hidp = ws + NREP * 2 * 1536;   // [1875] tagged hid values

  // weights: 48 rows (r=u*4+g) x 1536 halves (1500 + zero pad) = 147,456 B
  __shared__ __align__(16) _Float16 lds_wh[48 * 1536];
  __shared__ __align__(16) _Float16 lds_hh[1536];  // h(t) as fp16
  __shared__ __align__(16) float    lds_hf[1536];  // h(TT) fp32 for MLP
  __shared__ float lds_xp[2][48];                  // x-proj dbuf: [par][g*12+u]
  __shared__ float lds_gs[4][12];                  // gate sums: [g][u]
  float* lds_hd = (float*)lds_wh;                  // alias (block 0, post-loop)
  // total ~157.2 KB < 160 KiB -> exactly 1 block/CU (lockstep chain intact)

  // ---- stage W_hh slice into LDS, converting fp32 -> fp16 ----
  for (int hi = tid; hi < 48 * 1536; hi += NT) {
    const int r = hi / 1536, k = hi - r * 1536;
    const int u = r >> 2, g = r & 3;
    const size_t grow = (size_t)(g * HH + bid * 12 + u) * HH;
    const float v = (k < HH) ? Whh[grow + k] : 0.f;
    lds_wh[hi] = (_Float16)v;
  }

  // matvec bases (waves 0..5): wave wv owns units 2wv, 2wv+1; 192 b128/row
  const int uu = (wv < 6) ? wv : 0;
  const uv4* wpA = ((const uv4*)lds_wh) + (size_t)(2 * uu) * 4 * 192;
  const uv4* wpB = wpA + 4 * 192;
  const uv4* hp = (const uv4*)lds_hh;

  // ---- wave 6 lanes 0..47: persistent Wih row (g=ln/12, u=ln%12) + x(0) ----
  float4 wx0, wx1, wx2, wx3, wx4;
  float4 xr0, xr1, xr2, xr3, xr4;
  float bias = 0.f;
  if (wv == 6 && ln < 48) {
    const int g = ln / 12, u = ln - g * 12;
    const int row = g * HH + bid * 12 + u;
    const float4* sp = (const float4*)(Wih + row * 20);
    wx0 = sp[0]; wx1 = sp[1]; wx2 = sp[2]; wx3 = sp[3]; wx4 = sp[4];
    bias = bih[row] + bhh[row];
    const float4* xx = (const float4*)x;
    xr0 = xx[0]; xr1 = xx[1]; xr2 = xx[2]; xr3 = xx[3]; xr4 = xx[4];
  }

  float c = 0.f;  // cell state: wave 7 lanes 0..11 (unit = ln)

  // init publish: h(0)=0 with tag 1 into ALL replicas, slot 0
  if (tid < 12 * NREP)
    AST4(pub + (tid / 12) * 3072 + 12 * bid + (tid % 12), 1u);

  __syncthreads();   // weights staged

  // this block's poll replica
  unsigned* myrep = pub + (bid & (NREP - 1)) * 3072;

  for (int t = 0; t < TT; ++t) {
    const int s = t & 1;
    const unsigned tag = (unsigned)((t + 1) & 15);

    // ================= P phase (pre-A) =================
    uv4 pw[24];
    if (wv < 6) {
      // prefetch ALL 24 weight b128 (96 VGPRs) — overlaps the poll below
      #pragma unroll
      for (int g = 0; g < 4; ++g) {
        #pragma unroll
        for (int m = 0; m < 3; ++m) {
          pw[g * 3 + m]      = wpA[g * 192 + ln + 64 * m];
          pw[12 + g * 3 + m] = wpB[g * 192 + ln + 64 * m];
        }
      }
    } else {
      if (wv == 6 && ln < 48) {
        // x-projection for step t (from registers, h-independent)
        float sx = bias;
        sx += wx0.x*xr0.x + wx0.y*xr0.y + wx0.z*xr0.z + wx0.w*xr0.w;
        sx += wx1.x*xr1.x + wx1.y*xr1.y + wx1.z*xr1.z + wx1.w*xr1.w;
        sx += wx2.x*xr2.x + wx2.y*xr2.y + wx2.z*xr2.z + wx2.w*xr2.w;
        sx += wx3.x*xr3.x + wx3.y*xr3.y + wx3.z*xr3.z + wx3.w*xr3.w;
        sx += wx4.x*xr4.x + wx4.y*xr4.y + wx4.z*xr4.z + wx4.w*xr4.w;
        lds_xp[s][ln] = sx;
      }
      // ---- coalesced tagged poll of replica bid&7 (R12 structure) ----
      const int p4 = (tid - 384) << 2;        // 0,4,...,508
      unsigned* base = myrep + s * 1536;
      uv4 v0, v1, v2;
      for (;;) {
        poll3(base + p4, base + p4 + 512, base + p4 + 1024, v0, v1, v2);
        unsigned miss = ((v0.x & 15u) ^ tag) | ((v0.y & 15u) ^ tag)
                      | ((v0.z & 15u) ^ tag) | ((v0.w & 15u) ^ tag)
                      | ((v1.x & 15u) ^ tag) | ((v1.y & 15u) ^ tag)
                      | ((v1.z & 15u) ^ tag) | ((v1.w & 15u) ^ tag);
        if (p4 + 1024 < HH)   // chunk-uniform: 1500 = 4*375
          miss |= ((v2.x & 15u) ^ tag) | ((v2.y & 15u) ^ tag)
                | ((v2.z & 15u) ^ tag) | ((v2.w & 15u) ^ tag);
        if (!__any(miss != 0u)) break;
        __builtin_amdgcn_s_sleep(1);
      }
      *(h4f*)(lds_hh + p4)       = cvt4h(v0);
      *(h4f*)(lds_hh + p4 + 512) = cvt4h(v1);
      h4f z = {(_Float16)0.f, (_Float16)0.f, (_Float16)0.f, (_Float16)0.f};
      *(h4f*)(lds_hh + p4 + 1024) = (p4 + 1024 < HH) ? cvt4h(v2) : z;
    }
    __syncthreads();   // ---- A: h(t) fp16, xp(t) staged ----

    // ================= M phase =================
    if (wv < 6) {
      uv4 hv[3];
      #pragma unroll
      for (int m = 0; m < 3; ++m) hv[m] = hp[ln + 64 * m];
      float a0[4] = {0.f, 0.f, 0.f, 0.f};
      float a1[4] = {0.f, 0.f, 0.f, 0.f};
      #pragma unroll
      for (int g = 0; g < 4; ++g) {
        #pragma unroll
        for (int m = 0; m < 3; ++m) {
          const uv4 h = hv[m];
          const uv4 qa = pw[g * 3 + m];
          a0[g] = dot2(qa.x, h.x, a0[g]);
          a0[g] = dot2(qa.y, h.y, a0[g]);
          a0[g] = dot2(qa.z, h.z, a0[g]);
          a0[g] = dot2(qa.w, h.w, a0[g]);
          const uv4 qb = pw[12 + g * 3 + m];
          a1[g] = dot2(qb.x, h.x, a1[g]);
          a1[g] = dot2(qb.y, h.y, a1[g]);
          a1[g] = dot2(qb.z, h.z, a1[g]);
          a1[g] = dot2(qb.w, h.w, a1[g]);
        }
      }
      // fold-select reduce (x2 units)
      #pragma unroll
      for (int g = 0; g < 4; ++g) {
        a0[g] += __shfl_xor(a0[g], 16, 64);
        a0[g] += __shfl_xor(a0[g], 32, 64);
        a1[g] += __shfl_xor(a1[g], 16, 64);
        a1[g] += __shfl_xor(a1[g], 32, 64);
      }
      const int q4 = ln >> 4;
      float v0 = (q4 == 0) ? a0[0] : (q4 == 1) ? a0[1] : (q4 == 2) ? a0[2] : a0[3];
      float v1 = (q4 == 0) ? a1[0] : (q4 == 1) ? a1[1] : (q4 == 2) ? a1[2] : a1[3];
      #pragma unroll
      for (int off = 1; off <= 8; off <<= 1) {
        v0 += __shfl_xor(v0, off, 64);
        v1 += __shfl_xor(v1, off, 64);
      }
      if ((ln & 15) == 0) {
        lds_gs[q4][2 * wv]     = v0;
        lds_gs[q4][2 * wv + 1] = v1;
      }
    } else if (wv == 6 && ln < 48 && (t + 1) < TT) {
      // prefetch x(t+1) while waves 0-5 compute
      const float4* xx = (const float4*)(x + 20 * (t + 1));
      xr0 = xx[0]; xr1 = xx[1]; xr2 = xx[2]; xr3 = xx[3]; xr4 = xx[4];
    }
    __syncthreads();   // ---- B: gate sums ready ----

    // ================= G phase: wave 7 only =================
    if (wv == 7) {
      unsigned bits = 0u;
      if (ln < 12) {
        const int u = ln;
        const float zi = lds_gs[0][u] + lds_xp[s][0 + u];
        const float zf = lds_gs[1][u] + lds_xp[s][12 + u];
        const float zg = lds_gs[2][u] + lds_xp[s][24 + u];
        const float zo = lds_gs[3][u] + lds_xp[s][36 + u];
        const float ig = fast_sigmoid(zi);
        const float fg = fast_sigmoid(zf);
        const float gg = fast_tanh(zg);
        const float og = fast_sigmoid(zo);
        c = fg * c + ig * gg;
        const float hn = og * fast_tanh(c);
        bits = (__float_as_uint(hn) & ~15u) | (unsigned)((t + 2) & 15);
      }
      // publish 12 tagged dwords x 8 replicas: lanes 0..47, dwordx2 each
      const int m6 = ln % 6;
      const unsigned d0 = (unsigned)__shfl((int)bits, 2 * m6, 64);
      const unsigned d1 = (unsigned)__shfl((int)bits, 2 * m6 + 1, 64);
      if (ln < 48) {
        const int rep = ln / 6;
        const unsigned long long dd =
            (unsigned long long)d0 | ((unsigned long long)d1 << 32);
        AST8((unsigned long long*)(pub + rep * 3072 + ((t + 1) & 1) * 1536 +
                                   12 * bid + 2 * m6), dd);
      }
    }
  }

  // ---- final gather h(TT) fp32 into lds_hf (slot 0, tag 1) ----
  {
    const unsigned tagf = (unsigned)((TT + 1) & 15);
    if (tid < 375) {
      const unsigned* ap = myrep + (tid << 2);   // slot 0 of own replica
      uv4 v;
      for (;;) {
        asm volatile("global_load_dwordx4 %0, %1, off sc0 sc1\n\t"
                     "s_waitcnt vmcnt(0)"
                     : "=&v"(v) : "v"(ap) : "memory");
        const unsigned miss = ((v.x & 15u) ^ tagf) | ((v.y & 15u) ^ tagf)
                            | ((v.z & 15u) ^ tagf) | ((v.w & 15u) ^ tagf);
        if (!miss) break;
        __builtin_amdgcn_s_sleep(1);
      }
      float4 f = {__uint_as_float(v.x), __uint_as_float(v.y),
                  __uint_as_float(v.z), __uint_as_float(v.w)};
      *(float4*)(lds_hf + (tid << 2)) = f;
    } else if (tid < 384) {
      float4 z4 = {0.f, 0.f, 0.f, 0.f};
      *(float4*)(lds_hf + (tid << 2)) = z4;
    }
  }
  __syncthreads();

  // ---- MLP layer 1: 15 rows/block, r = bid + 125*k, k = wv, wv+8 ----
  {
    const float4* h4 = (const float4*)lds_hf;
    for (int k = wv; k < 15; k += 8) {
      const int r = bid + NB * k;
      const float4* wrow = (const float4*)(W1 + (size_t)r * HH);
      float ss = 0.f;
      #pragma unroll
      for (int m = 0; m < 6; ++m) {
        const int idx = ln + 64 * m;
        if (idx < 375) {
          const float4 a = wrow[idx], hv = h4[idx];
          ss += a.x*hv.x + a.y*hv.y + a.z*hv.z + a.w*hv.w;
        }
      }
      #pragma unroll
      for (int off = 32; off > 0; off >>= 1) ss += __shfl_xor(ss, off, 64);
      if (ln == 0) {
        const float vv = ss + b1[r];
        AST4(hidp + r, (__float_as_uint(vv) & ~15u) | 5u);  // tag 5 != poison 10
      }
    }
  }
  if (bid != 0) return;

  // ---- block 0: gather hid (into lds_wh alias), MLP layer 2, write out ----
  __syncthreads();
  for (int j = tid; j < 1875; j += NT) {
    unsigned bts;
    for (;;) {
      bts = ALD4(hidp + j);
      if ((bts & 15u) == 5u) break;
      __builtin_amdgcn_s_sleep(1);
    }
    lds_hd[j] = __uint_as_float(bts);
  }
  __syncthreads();

  for (int r = wv; r < 20; r += 8) {
    float ss = 0.f;
    for (int k = ln; k < 1875; k += 64)
      ss = fmaf(W2[(size_t)r * 1875 + k], lds_hd[k], ss);
    #pragma unroll
    for (int off = 32; off > 0; off >>= 1) ss += __shfl_xor(ss, off, 64);
    if (ln == 0) out[r] = ss + b2[r];
  }
}

extern "C" void kernel_launch(void* const* d_in, const int* in_sizes, int n_in,
                              void* d_out, int out_size, void* d_ws, size_t ws_size,
                              hipStream_t stream) {
  const float* x   = (const float*)d_in[0];
  const float* Wih = (const float*)d_in[1];
  const float* Whh = (const float*)d_in[2];
  const float* bih = (const float*)d_in[3];
  const float* bhh = (const float*)d_in[4];
  const float* W1  = (const float*)d_in[5];
  const float* b1  = (const float*)d_in[6];
  const float* W2  = (const float*)d_in[7];
  const float* b2  = (const float*)d_in[8];
  float* out   = (float*)d_out;
  unsigned* ws = (unsigned*)d_ws;   // uses ~106 KB (8 pub replicas + hidp)

  // 125 blocks x 512 threads, ~157 KB LDS (1 block/CU), 125 <= 256 CUs:
  // all blocks co-resident -> the tagged exchange cannot deadlock.
  hipLaunchKernelGGL(lstm_fused, dim3(NB), dim3(NT), 0, stream,
                     x, Wih, Whh, bih, bhh, W1, b1, W2, b2, out, ws);
}